// Round 4
// baseline (107.670 us; speedup 1.0000x reference)
//
#include <hip/hip_runtime.h>
#include <hip/hip_bf16.h>
#include <cstdint>

typedef unsigned short u16;
typedef __bf16 bf16x8 __attribute__((ext_vector_type(8)));
typedef u16 u16x8 __attribute__((ext_vector_type(8)));
typedef unsigned u32x4 __attribute__((ext_vector_type(4)));
typedef float f32x4 __attribute__((ext_vector_type(4)));
typedef float f32x16 __attribute__((ext_vector_type(16)));

#define B_ 2
#define S_ 2048
#define H_ 16
#define HS_ 64
#define EMB_ 1024
#define QSCALE 0.022097086912079608f  /* 1/sqrt(2048), folded into Q */

static __device__ __forceinline__ u16 f2bf(float f) {
  unsigned int u = __float_as_uint(f);
  u += 0x7fffu + ((u >> 16) & 1u);   // RNE
  return (u16)(u >> 16);
}

static __device__ __forceinline__ f32x4 mfma16(u16x8 a, u16x8 b, f32x4 c) {
  return __builtin_amdgcn_mfma_f32_16x16x32_bf16(
      __builtin_bit_cast(bf16x8, a), __builtin_bit_cast(bf16x8, b), c, 0, 0, 0);
}
static __device__ __forceinline__ f32x16 mfma32(u16x8 a, u16x8 b, f32x16 c) {
  return __builtin_amdgcn_mfma_f32_32x32x16_bf16(
      __builtin_bit_cast(bf16x8, a), __builtin_bit_cast(bf16x8, b), c, 0, 0, 0);
}

// XOR-swizzled address into a tile with 128B row stride.
static __device__ __forceinline__ char* swzb(void* base, int row, int colbyte) {
  return (char*)base + ((row * 128 + colbyte) ^ ((row & 7) << 4));
}
static __device__ __forceinline__ u16x8* swzp(void* base, int row, int colbyte) {
  return (u16x8*)swzb(base, row, colbyte);
}

// cvt_pk two f32 pairs to packed bf16 words, then permlane32_swap.
static __device__ __forceinline__ void pk_swap(float a0, float a1, float b0, float b1,
                                               unsigned& x, unsigned& y) {
  unsigned A, Bv;
  asm("v_cvt_pk_bf16_f32 %0, %1, %2" : "=v"(A) : "v"(a0), "v"(a1));
  asm("v_cvt_pk_bf16_f32 %0, %1, %2" : "=v"(Bv) : "v"(b0), "v"(b1));
  asm("v_permlane32_swap_b32 %0, %1" : "+v"(A), "+v"(Bv));
  x = A; y = Bv;
}

// ---------------- K0: Wo[k][n] fp32 -> Wot[n][k] bf16 ----------------
__global__ __launch_bounds__(256) void k_transpose_wo(const float* __restrict__ Wo,
                                                      u16* __restrict__ Wot) {
  __shared__ __align__(16) u16 T[64][72];
  const int kb = blockIdx.y * 64, nb = blockIdx.x * 64;
  const int r = threadIdx.x >> 2;
  const int c0 = (threadIdx.x & 3) << 4;
  const float* src = Wo + (size_t)(kb + r) * EMB_ + nb + c0;
#pragma unroll
  for (int i = 0; i < 16; i += 4) {
    float4 f = *(const float4*)(src + i);
    T[c0 + i + 0][r] = f2bf(f.x);
    T[c0 + i + 1][r] = f2bf(f.y);
    T[c0 + i + 2][r] = f2bf(f.z);
    T[c0 + i + 3][r] = f2bf(f.w);
  }
  __syncthreads();
  u16* dst = Wot + (size_t)(nb + r) * EMB_ + kb + c0;
  *(u16x8*)(dst)     = *(const u16x8*)&T[r][c0];
  *(u16x8*)(dst + 8) = *(const u16x8*)&T[r][c0 + 8];
}

// ---------------- K1: per-head projections ----------------
// Qo (pre-scaled by QSCALE), Ko: [bh][s][64]; Vt: [bh][e][s] (transposed)
__global__ __launch_bounds__(256) void k_proj(
    const float* __restrict__ xq, const float* __restrict__ xk, const float* __restrict__ xv,
    const float* __restrict__ Wq, const float* __restrict__ Wk, const float* __restrict__ Wv,
    u16* __restrict__ Qo, u16* __restrict__ Ko, u16* __restrict__ Vt) {
  __shared__ __align__(16) u16 X[3][64][64];
  __shared__ __align__(16) u16 WT[3][64][64];
  const int sb = blockIdx.x;
  const int bh = blockIdx.y;
  const int b = bh >> 4;
  const int h = bh & 15;
  const int t = threadIdx.x;
  const int r = t >> 2;
  const int c0 = (t & 3) << 4;
  const float* xs[3] = {xq, xk, xv};
  const float* wsrc[3] = {Wq, Wk, Wv};
#pragma unroll
  for (int tn = 0; tn < 3; ++tn) {
    const float* src = xs[tn] + ((size_t)(b * S_ + sb * 64 + r)) * HS_ + c0;
#pragma unroll
    for (int i = 0; i < 16; i += 8) {
      float4 fa = *(const float4*)(src + i);
      float4 fb = *(const float4*)(src + i + 4);
      u16x8 v = {f2bf(fa.x), f2bf(fa.y), f2bf(fa.z), f2bf(fa.w),
                 f2bf(fb.x), f2bf(fb.y), f2bf(fb.z), f2bf(fb.w)};
      *swzp(&X[tn][0][0], r, (c0 + i) * 2) = v;
    }
    const float* wsp = wsrc[tn] + ((size_t)(h * HS_ + r)) * HS_ + c0;
#pragma unroll
    for (int i = 0; i < 16; i += 4) {
      float4 f = *(const float4*)(wsp + i);
      *(u16*)swzb(&WT[tn][0][0], c0 + i + 0, r * 2) = f2bf(f.x);
      *(u16*)swzb(&WT[tn][0][0], c0 + i + 1, r * 2) = f2bf(f.y);
      *(u16*)swzb(&WT[tn][0][0], c0 + i + 2, r * 2) = f2bf(f.z);
      *(u16*)swzb(&WT[tn][0][0], c0 + i + 3, r * 2) = f2bf(f.w);
    }
  }
  __syncthreads();
  const int lane = t & 63, wv = t >> 6;
  const int lq = lane & 15, lg = lane >> 4;
#pragma unroll
  for (int tn = 0; tn < 2; ++tn) {
    u16x8 a0 = *swzp(&X[tn][0][0], wv * 16 + lq, lg * 16);
    u16x8 a1 = *swzp(&X[tn][0][0], wv * 16 + lq, 64 + lg * 16);
    u16* outp = (tn == 0) ? Qo : Ko;
    const float osc = (tn == 0) ? QSCALE : 1.0f;
#pragma unroll
    for (int et = 0; et < 4; ++et) {
      u16x8 b0 = *swzp(&WT[tn][0][0], et * 16 + lq, lg * 16);
      u16x8 b1 = *swzp(&WT[tn][0][0], et * 16 + lq, 64 + lg * 16);
      f32x4 acc = {0.f, 0.f, 0.f, 0.f};
      acc = mfma16(a0, b0, acc);
      acc = mfma16(a1, b1, acc);
#pragma unroll
      for (int rr = 0; rr < 4; ++rr) {
        int s = sb * 64 + wv * 16 + lg * 4 + rr;
        outp[((size_t)(bh * S_ + s)) * HS_ + et * 16 + lq] = f2bf(acc[rr] * osc);
      }
    }
  }
  u16x8 xb0 = *swzp(&X[2][0][0], wv * 16 + lq, lg * 16);
  u16x8 xb1 = *swzp(&X[2][0][0], wv * 16 + lq, 64 + lg * 16);
#pragma unroll
  for (int et = 0; et < 4; ++et) {
    u16x8 a0 = *swzp(&WT[2][0][0], et * 16 + lq, lg * 16);
    u16x8 a1 = *swzp(&WT[2][0][0], et * 16 + lq, 64 + lg * 16);
    f32x4 acc = {0.f, 0.f, 0.f, 0.f};
    acc = mfma16(a0, xb0, acc);
    acc = mfma16(a1, xb1, acc);
#pragma unroll
    for (int rr = 0; rr < 4; ++rr) {
      int e = et * 16 + lg * 4 + rr;
      int s = sb * 64 + wv * 16 + lq;
      Vt[((size_t)(bh * HS_ + e)) * S_ + s] = f2bf(acc[rr]);
    }
  }
}

// ---------------- K2: causal flash attention, barrier-free kv-split ----------------
// Block = one 32-row q-tile (t of 64 per bh); 2 waves split the kv range and run
// independently (K/V fragments read directly from L2; no LDS, no barriers in loop).
// Partials merged once at the end via LDS.
__global__ __launch_bounds__(128) void k_attn(
    const u16* __restrict__ Q, const u16* __restrict__ K, const u16* __restrict__ Vt,
    u16* __restrict__ Co) {
  __shared__ float Xch[64][34];              // wave1 partials (o0,o1,m,l)
  __shared__ __align__(16) u16 Osw[32][64];  // wave0 output transpose buffer
  const int bid = blockIdx.x;
  const int xcd = bid & 7, idx = bid >> 3;   // idx 0..255
  const int bh = (xcd << 2) | (idx & 3);     // 4 bh per XCD (L2 locality)
  const int t = 63 - (idx >> 2);             // q-tile, big first
  const int b = bh >> 4, h = bh & 15;
  const int w = threadIdx.x >> 6;            // wave 0/1
  const int l = threadIdx.x & 63;
  const int lq = l & 31, hi = l >> 5;
  const int qg = t * 32 + lq;                // this lane's q row
  const int n = (t >> 1) + 1;                // kv 64-tiles needed
  const int mid = n >> 1;
  const int jbeg = w ? mid : 0;
  const int jend = w ? n : mid;
  const float NEG = -3.0e38f;

  const u16* Qb = Q + (size_t)bh * S_ * HS_;
  const u16* Kb = K + (size_t)bh * S_ * HS_;
  const u16* Vb = Vt + (size_t)bh * HS_ * S_;

  // Q fragments (B-operand): Q[q=lq col][d = tt*16 + hi*8 + i]
  u16x8 qf[4];
  {
    const u16* qp = Qb + (size_t)qg * HS_ + hi * 8;
#pragma unroll
    for (int tt = 0; tt < 4; ++tt) qf[tt] = *(const u16x8*)(qp + tt * 16);
  }

  f32x16 o0, o1;
#pragma unroll
  for (int r = 0; r < 16; ++r) { o0[r] = 0.f; o1[r] = 0.f; }
  float m = NEG, ll = 0.f;

  // per-lane invariant bases
  const u16* kptr = Kb + (size_t)lq * HS_ + hi * 8;   // + j*64*HS_ ; +32*HS_ hi-rows
  const u16* vptr = Vb + (size_t)lq * S_ + hi * 8;    // + j*64 ; +32*S_ hi-rows

  u16x8 kl[4], kh[4], vl[4], vh[4];
  if (jbeg < jend) {  // prologue K load
    const u16* p = kptr + (size_t)jbeg * 64 * HS_;
#pragma unroll
    for (int tt = 0; tt < 4; ++tt) {
      kl[tt] = *(const u16x8*)(p + tt * 16);
      kh[tt] = *(const u16x8*)(p + 32 * HS_ + tt * 16);
    }
  }

  for (int j = jbeg; j < jend; ++j) {
    const bool diag = (j == n - 1);              // only in wave1's last iter
    const bool half2 = !(diag && !(t & 1));      // skip kv[32,64) when fully masked
    // V loads for this tile (consumed after softmax — latency hidden)
    {
      const u16* pv = vptr + j * 64;
#pragma unroll
      for (int kb = 0; kb < 4; ++kb) {
        vl[kb] = *(const u16x8*)(pv + kb * 16);
        vh[kb] = *(const u16x8*)(pv + 32 * S_ + kb * 16);
      }
    }
    // QK^T swapped: S^T[kv][q] += K[kv][d] * Q[q][d]
    f32x16 s0, s1;
#pragma unroll
    for (int r = 0; r < 16; ++r) { s0[r] = 0.f; s1[r] = 0.f; }
    __builtin_amdgcn_s_setprio(1);
    s0 = mfma32(kl[0], qf[0], s0);
    s0 = mfma32(kl[1], qf[1], s0);
    s0 = mfma32(kl[2], qf[2], s0);
    s0 = mfma32(kl[3], qf[3], s0);
    if (half2) {
      s1 = mfma32(kh[0], qf[0], s1);
      s1 = mfma32(kh[1], qf[1], s1);
      s1 = mfma32(kh[2], qf[2], s1);
      s1 = mfma32(kh[3], qf[3], s1);
    }
    __builtin_amdgcn_s_setprio(0);
    // prefetch next K tile (current kl/kh already consumed by issued MFMAs)
    if (j + 1 < jend) {
      const u16* p = kptr + (size_t)(j + 1) * 64 * HS_;
#pragma unroll
      for (int tt = 0; tt < 4; ++tt) {
        kl[tt] = *(const u16x8*)(p + tt * 16);
        kh[tt] = *(const u16x8*)(p + 32 * HS_ + tt * 16);
      }
    }
    if (diag) {  // causal mask; kv row = (r&3)+8*(r>>2)+4*hi
      if (!(t & 1)) {
#pragma unroll
        for (int r = 0; r < 16; ++r) {
          int kv = j * 64 + (r & 3) + 8 * (r >> 2) + 4 * hi;
          if (kv > qg) s0[r] = NEG;
        }
      } else {
#pragma unroll
        for (int r = 0; r < 16; ++r) {
          int kv = j * 64 + 32 + (r & 3) + 8 * (r >> 2) + 4 * hi;
          if (kv > qg) s1[r] = NEG;
        }
      }
    }
    // online softmax (lane pair l / l^32 share q column lq)
    float pm = NEG;
#pragma unroll
    for (int r = 0; r < 16; ++r) pm = fmaxf(pm, s0[r]);
    if (half2) {
#pragma unroll
      for (int r = 0; r < 16; ++r) pm = fmaxf(pm, s1[r]);
    }
    pm = fmaxf(pm, __shfl_xor(pm, 32));
    if (__any(pm > m + 8.0f)) {   // T13 defer-max
      float mn = fmaxf(m, pm);
      float scl = __expf(m - mn);
#pragma unroll
      for (int r = 0; r < 16; ++r) { o0[r] *= scl; o1[r] *= scl; }
      ll *= scl;
      m = mn;
    }
    float ps = 0.f;
#pragma unroll
    for (int r = 0; r < 16; ++r) { s0[r] = __expf(s0[r] - m); ps += s0[r]; }
    if (half2) {
#pragma unroll
      for (int r = 0; r < 16; ++r) { s1[r] = __expf(s1[r] - m); ps += s1[r]; }
    }
    ps += __shfl_xor(ps, 32);
    ll += ps;
    // T12: pack P into PV B-fragments
    u16x8 pf0, pf1, pf2, pf3;
    {
      unsigned w0, w1, w2, w3;
      pk_swap(s0[0], s0[1], s0[4], s0[5], w0, w2);
      pk_swap(s0[2], s0[3], s0[6], s0[7], w1, w3);
      pf0 = __builtin_bit_cast(u16x8, (u32x4){w0, w1, w2, w3});
      pk_swap(s0[8], s0[9], s0[12], s0[13], w0, w2);
      pk_swap(s0[10], s0[11], s0[14], s0[15], w1, w3);
      pf1 = __builtin_bit_cast(u16x8, (u32x4){w0, w1, w2, w3});
      if (half2) {
        pk_swap(s1[0], s1[1], s1[4], s1[5], w0, w2);
        pk_swap(s1[2], s1[3], s1[6], s1[7], w1, w3);
        pf2 = __builtin_bit_cast(u16x8, (u32x4){w0, w1, w2, w3});
        pk_swap(s1[8], s1[9], s1[12], s1[13], w0, w2);
        pk_swap(s1[10], s1[11], s1[14], s1[15], w1, w3);
        pf3 = __builtin_bit_cast(u16x8, (u32x4){w0, w1, w2, w3});
      }
    }
    // PV: O^T[e][q] += Vt[e][kv] * P[kv][q]
    __builtin_amdgcn_s_setprio(1);
    o0 = mfma32(vl[0], pf0, o0);
    o1 = mfma32(vh[0], pf0, o1);
    o0 = mfma32(vl[1], pf1, o0);
    o1 = mfma32(vh[1], pf1, o1);
    if (half2) {
      o0 = mfma32(vl[2], pf2, o0);
      o1 = mfma32(vh[2], pf2, o1);
      o0 = mfma32(vl[3], pf3, o0);
      o1 = mfma32(vh[3], pf3, o1);
    }
    __builtin_amdgcn_s_setprio(0);
  }

  // ---- combine the two kv-halves, then write ----
  if (w == 1) {
#pragma unroll
    for (int r = 0; r < 16; ++r) { Xch[l][r] = o0[r]; Xch[l][16 + r] = o1[r]; }
    Xch[l][32] = m;
    Xch[l][33] = ll;
  }
  __syncthreads();
  if (w == 0) {
    float m1 = Xch[l][32], l1 = Xch[l][33];
    float mm = fmaxf(m, m1);
    float a0 = __expf(m - mm), a1 = __expf(m1 - mm);
    float inv = 1.0f / (ll * a0 + l1 * a1);
#pragma unroll
    for (int r = 0; r < 16; ++r) {
      float e0 = (o0[r] * a0 + Xch[l][r] * a1) * inv;
      float e1 = (o1[r] * a0 + Xch[l][16 + r] * a1) * inv;
      int drow = (r & 3) + 8 * (r >> 2) + 4 * hi;
      *(u16*)swzb(Osw, lq, drow * 2) = f2bf(e0);
      *(u16*)swzb(Osw, lq, (32 + drow) * 2) = f2bf(e1);
    }
    // same-wave LDS write->read: compiler inserts lgkmcnt
    u16* dst = Co + ((size_t)(b * S_ + qg)) * EMB_ + h * HS_ + hi * 32;
#pragma unroll
    for (int k = 0; k < 4; ++k) {
      u16x8 vv = *swzp(Osw, lq, (hi * 32 + k * 8) * 2);
      *(u16x8*)(dst + k * 8) = vv;
    }
  }
}

// ---------------- K3: out = concat @ Wo + bo (fp32 out), 64x128 tiles ----------------
__global__ __launch_bounds__(256) void k_outproj(
    const u16* __restrict__ Cc, const u16* __restrict__ Wot,
    const float* __restrict__ bo, float* __restrict__ out) {
  __shared__ __align__(16) u16 As[64][64];
  __shared__ __align__(16) u16 Bs[128][64];
  const int bid = blockIdx.x;
  const int xcd = bid & 7, sl = bid >> 3;   // sl 0..63
  const int mb = (xcd << 3) | (sl >> 3);    // 0..63 (8 M-tiles per XCD)
  const int nb = sl & 7;                    // 0..7
  const int t = threadIdx.x;
  const int lane = t & 63, wv = t >> 6;
  const int lq = lane & 15, lg = lane >> 4;
  const int wr = wv >> 1, wc = wv & 1;      // 2(M) x 2(N) waves
  const int srA = t >> 2, scA = (t & 3) << 4;   // A staging: 64 rows x 16 elems
  const int srB = t >> 1, scB = (t & 1) << 5;   // B staging: 128 rows x 32 elems
  f32x4 acc[2][4];
#pragma unroll
  for (int mi = 0; mi < 2; ++mi)
#pragma unroll
    for (int ni = 0; ni < 4; ++ni) { f32x4 z = {0.f, 0.f, 0.f, 0.f}; acc[mi][ni] = z; }
  const u16* abase = Cc + ((size_t)(mb * 64 + srA)) * EMB_ + scA;
  const u16* bbase = Wot + ((size_t)(nb * 128 + srB)) * EMB_ + scB;
  u16x8 ar[2], br[4];
#pragma unroll
  for (int q = 0; q < 2; ++q) ar[q] = *(const u16x8*)(abase + q * 8);
#pragma unroll
  for (int q = 0; q < 4; ++q) br[q] = *(const u16x8*)(bbase + q * 8);
  for (int kt = 0; kt < 16; ++kt) {
    __syncthreads();
#pragma unroll
    for (int q = 0; q < 2; ++q) *swzp(As, srA, (scA + q * 8) * 2) = ar[q];
#pragma unroll
    for (int q = 0; q < 4; ++q) *swzp(Bs, srB, (scB + q * 8) * 2) = br[q];
    __syncthreads();
    if (kt < 15) {
#pragma unroll
      for (int q = 0; q < 2; ++q) ar[q] = *(const u16x8*)(abase + (kt + 1) * 64 + q * 8);
#pragma unroll
      for (int q = 0; q < 4; ++q) br[q] = *(const u16x8*)(bbase + (kt + 1) * 64 + q * 8);
    }
#pragma unroll
    for (int kf = 0; kf < 2; ++kf) {
      u16x8 af[2], bf[4];
#pragma unroll
      for (int mi = 0; mi < 2; ++mi)
        af[mi] = *swzp(As, wr * 32 + mi * 16 + lq, kf * 64 + lg * 16);
#pragma unroll
      for (int ni = 0; ni < 4; ++ni)
        bf[ni] = *swzp(Bs, wc * 64 + ni * 16 + lq, kf * 64 + lg * 16);
#pragma unroll
      for (int mi = 0; mi < 2; ++mi)
#pragma unroll
        for (int ni = 0; ni < 4; ++ni)
          acc[mi][ni] = mfma16(af[mi], bf[ni], acc[mi][ni]);
    }
  }
#pragma unroll
  for (int mi = 0; mi < 2; ++mi) {
#pragma unroll
    for (int ni = 0; ni < 4; ++ni) {
      int col = nb * 128 + wc * 64 + ni * 16 + lq;
      float bv = bo[col];
#pragma unroll
      for (int rr = 0; rr < 4; ++rr) {
        int row = mb * 64 + wr * 32 + mi * 16 + lg * 4 + rr;
        out[(size_t)row * EMB_ + col] = acc[mi][ni][rr] + bv;
      }
    }
  }
}

extern "C" void kernel_launch(void* const* d_in, const int* in_sizes, int n_in,
                              void* d_out, int out_size, void* d_ws, size_t ws_size,
                              hipStream_t stream) {
  const float* xk = (const float*)d_in[0];
  const float* xv = (const float*)d_in[1];
  const float* xq = (const float*)d_in[2];
  const float* Wk = (const float*)d_in[3];
  const float* Wv = (const float*)d_in[4];
  const float* Wq = (const float*)d_in[5];
  const float* Wo = (const float*)d_in[6];
  const float* bo = (const float*)d_in[7];
  float* out = (float*)d_out;
  char* ws = (char*)d_ws;
  const size_t MB8 = (size_t)8 * 1024 * 1024;
  u16* Qw  = (u16*)(ws);             // [32][2048][64] bf16 (pre-scaled)
  u16* Kw  = (u16*)(ws + MB8);       // [32][2048][64]
  u16* Vtw = (u16*)(ws + 2 * MB8);   // [32][64][2048]
  u16* Cw  = (u16*)(ws + 3 * MB8);   // [2][2048][1024]
  u16* Wot = (u16*)(ws + 4 * MB8);   // [1024][1024]

  k_transpose_wo<<<dim3(16, 16), 256, 0, stream>>>(Wo, Wot);
  k_proj<<<dim3(32, 32), 256, 0, stream>>>(xq, xk, xv, Wq, Wk, Wv, Qw, Kw, Vtw);
  k_attn<<<2048, 128, 0, stream>>>(Qw, Kw, Vtw, Cw);
  k_outproj<<<512, 256, 0, stream>>>(Cw, Wot, bo, out);
}

// Round 5
// 88.273 us; speedup vs baseline: 1.2197x; 1.2197x over previous
//
#include <hip/hip_runtime.h>
#include <hip/hip_bf16.h>
#include <cstdint>

typedef unsigned short u16;
typedef __bf16 bf16x8 __attribute__((ext_vector_type(8)));
typedef u16 u16x8 __attribute__((ext_vector_type(8)));
typedef unsigned u32x4 __attribute__((ext_vector_type(4)));
typedef float f32x4 __attribute__((ext_vector_type(4)));
typedef float f32x16 __attribute__((ext_vector_type(16)));

#define B_ 2
#define S_ 2048
#define H_ 16
#define HS_ 64
#define EMB_ 1024
#define QSCALE 0.022097086912079608f  /* 1/sqrt(2048) */
#define LOG2E  1.4426950408889634f    /* folded into Q so softmax uses exp2 */

static __device__ __forceinline__ u16 f2bf(float f) {
  unsigned int u = __float_as_uint(f);
  u += 0x7fffu + ((u >> 16) & 1u);   // RNE
  return (u16)(u >> 16);
}

static __device__ __forceinline__ f32x4 mfma16(u16x8 a, u16x8 b, f32x4 c) {
  return __builtin_amdgcn_mfma_f32_16x16x32_bf16(
      __builtin_bit_cast(bf16x8, a), __builtin_bit_cast(bf16x8, b), c, 0, 0, 0);
}
static __device__ __forceinline__ f32x16 mfma32(u16x8 a, u16x8 b, f32x16 c) {
  return __builtin_amdgcn_mfma_f32_32x32x16_bf16(
      __builtin_bit_cast(bf16x8, a), __builtin_bit_cast(bf16x8, b), c, 0, 0, 0);
}

// XOR-swizzled address into a tile with 128B row stride (LDS bank-conflict fix).
static __device__ __forceinline__ char* swzb(void* base, int row, int colbyte) {
  return (char*)base + ((row * 128 + colbyte) ^ ((row & 7) << 4));
}
static __device__ __forceinline__ u16x8* swzp(void* base, int row, int colbyte) {
  return (u16x8*)swzb(base, row, colbyte);
}

// cvt_pk two f32 pairs to packed bf16 words, then permlane32_swap (T12).
static __device__ __forceinline__ void pk_swap(float a0, float a1, float b0, float b1,
                                               unsigned& x, unsigned& y) {
  unsigned A, Bv;
  asm("v_cvt_pk_bf16_f32 %0, %1, %2" : "=v"(A) : "v"(a0), "v"(a1));
  asm("v_cvt_pk_bf16_f32 %0, %1, %2" : "=v"(Bv) : "v"(b0), "v"(b1));
  asm("v_permlane32_swap_b32 %0, %1" : "+v"(A), "+v"(Bv));
  x = A; y = Bv;
}

// ---------------- K0: Wo[k][n] fp32 -> Wot[n][k] bf16 ----------------
__global__ __launch_bounds__(256) void k_transpose_wo(const float* __restrict__ Wo,
                                                      u16* __restrict__ Wot) {
  __shared__ __align__(16) u16 T[64][72];
  const int kb = blockIdx.y * 64, nb = blockIdx.x * 64;
  const int r = threadIdx.x >> 2;
  const int c0 = (threadIdx.x & 3) << 4;
  const float* src = Wo + (size_t)(kb + r) * EMB_ + nb + c0;
#pragma unroll
  for (int i = 0; i < 16; i += 4) {
    float4 f = *(const float4*)(src + i);
    T[c0 + i + 0][r] = f2bf(f.x);
    T[c0 + i + 1][r] = f2bf(f.y);
    T[c0 + i + 2][r] = f2bf(f.z);
    T[c0 + i + 3][r] = f2bf(f.w);
  }
  __syncthreads();
  u16* dst = Wot + (size_t)(nb + r) * EMB_ + kb + c0;
  *(u16x8*)(dst)     = *(const u16x8*)&T[r][c0];
  *(u16x8*)(dst + 8) = *(const u16x8*)&T[r][c0 + 8];
}

// ---------------- K1: projections -> FRAGMENT-MAJOR layouts ----------------
// Qf: [bh][t:64][slice:4][lane:64][8]   = Q[t*32+(l&31)][slice*16+(l>>5)*8+j] * QSCALE*LOG2E
// Kf: [bh][tau:64][slice:4][lane:64][8] = K[tau*32+(l&31)][slice*16+(l>>5)*8+j]
// Vf: [bh][j:32][eta:2][kap:4][lane:64][8] = Vt[eta*32+(l&31)][j*64+kap*16+(l>>5)*8+jj]
// Each fragment line is 1KB contiguous -> wave loads are perfectly coalesced.
__global__ __launch_bounds__(256) void k_proj(
    const float* __restrict__ xq, const float* __restrict__ xk, const float* __restrict__ xv,
    const float* __restrict__ Wq, const float* __restrict__ Wk, const float* __restrict__ Wv,
    u16* __restrict__ Qf, u16* __restrict__ Kf, u16* __restrict__ Vf) {
  __shared__ __align__(16) u16 Xb[64][64];
  __shared__ __align__(16) u16 Wb[64][64];   // Wb[e][d] = W[d][e]
  __shared__ __align__(16) u16 Tt[64][64];
  const int sb = blockIdx.x;   // s-block 0..31
  const int bh = blockIdx.y;   // 0..31
  const int b = bh >> 4, h = bh & 15;
  const int t = threadIdx.x;
  const int r = t >> 2, c0 = (t & 3) << 4;
  const int lane = t & 63, wv = t >> 6;
  const int lq = lane & 15, lg = lane >> 4;
  const int l31 = lane & 31, hi = lane >> 5;
  const float* xs[3] = {xq, xk, xv};
  const float* ws3[3] = {Wq, Wk, Wv};

  for (int tn = 0; tn < 3; ++tn) {
    __syncthreads();  // prev tensor's gathers done; Xb/Wb/Tt free
    const float* src = xs[tn] + ((size_t)(b * S_ + sb * 64 + r)) * HS_ + c0;
#pragma unroll
    for (int i = 0; i < 16; i += 8) {
      float4 fa = *(const float4*)(src + i);
      float4 fb = *(const float4*)(src + i + 4);
      u16x8 v = {f2bf(fa.x), f2bf(fa.y), f2bf(fa.z), f2bf(fa.w),
                 f2bf(fb.x), f2bf(fb.y), f2bf(fb.z), f2bf(fb.w)};
      *swzp(Xb, r, (c0 + i) * 2) = v;
    }
    const float* wsp = ws3[tn] + ((size_t)(h * HS_ + r)) * HS_ + c0;
#pragma unroll
    for (int i = 0; i < 16; i += 4) {
      float4 f = *(const float4*)(wsp + i);
      *(u16*)swzb(Wb, c0 + i + 0, r * 2) = f2bf(f.x);
      *(u16*)swzb(Wb, c0 + i + 1, r * 2) = f2bf(f.y);
      *(u16*)swzb(Wb, c0 + i + 2, r * 2) = f2bf(f.z);
      *(u16*)swzb(Wb, c0 + i + 3, r * 2) = f2bf(f.w);
    }
    __syncthreads();
    if (tn < 2) {
      // D[s][e] -> Tt[s][e]
      u16x8 a0 = *swzp(Xb, wv * 16 + lq, lg * 16);
      u16x8 a1 = *swzp(Xb, wv * 16 + lq, 64 + lg * 16);
      const float osc = (tn == 0) ? (QSCALE * LOG2E) : 1.0f;
#pragma unroll
      for (int et = 0; et < 4; ++et) {
        u16x8 b0 = *swzp(Wb, et * 16 + lq, lg * 16);
        u16x8 b1 = *swzp(Wb, et * 16 + lq, 64 + lg * 16);
        f32x4 acc = {0.f, 0.f, 0.f, 0.f};
        acc = mfma16(a0, b0, acc);
        acc = mfma16(a1, b1, acc);
#pragma unroll
        for (int rr = 0; rr < 4; ++rr)
          *(u16*)swzb(Tt, wv * 16 + lg * 4 + rr, (et * 16 + lq) * 2) = f2bf(acc[rr] * osc);
      }
    } else {
      // D[e][s] -> Tt[e][s]
      u16x8 xb0 = *swzp(Xb, wv * 16 + lq, lg * 16);
      u16x8 xb1 = *swzp(Xb, wv * 16 + lq, 64 + lg * 16);
#pragma unroll
      for (int et = 0; et < 4; ++et) {
        u16x8 a0 = *swzp(Wb, et * 16 + lq, lg * 16);
        u16x8 a1 = *swzp(Wb, et * 16 + lq, 64 + lg * 16);
        f32x4 acc = {0.f, 0.f, 0.f, 0.f};
        acc = mfma16(a0, xb0, acc);
        acc = mfma16(a1, xb1, acc);
#pragma unroll
        for (int rr = 0; rr < 4; ++rr)
          *(u16*)swzb(Tt, et * 16 + lg * 4 + rr, (wv * 16 + lq) * 2) = f2bf(acc[rr]);
      }
    }
    __syncthreads();
    // fragment gather + coalesced 16B store (wave wv owns slice/kappa = wv)
    if (tn < 2) {
      u16* dst = (tn == 0) ? Qf : Kf;
#pragma unroll
      for (int tl = 0; tl < 2; ++tl) {
        u16x8 v = *swzp(Tt, tl * 32 + l31, wv * 32 + hi * 16);
        size_t off = (((size_t)(bh * 64 + sb * 2 + tl)) * 4 + wv) * 512 + lane * 8;
        *(u16x8*)(dst + off) = v;
      }
    } else {
#pragma unroll
      for (int eta = 0; eta < 2; ++eta) {
        u16x8 v = *swzp(Tt, eta * 32 + l31, wv * 32 + hi * 16);
        size_t off = ((((size_t)(bh * 32 + sb)) * 2 + eta) * 4 + wv) * 512 + lane * 8;
        *(u16x8*)(Vf + off) = v;
      }
    }
  }
}

// ---------------- K2: causal flash attention, 1 independent wave / 32-row q-tile ----
// 2048 single-wave blocks, all co-resident (2 waves/SIMD). No LDS / barriers in loop;
// all operand loads are coalesced 1KB fragment lines (L2-resident). exp2-domain softmax.
__global__ __launch_bounds__(64) void k_attn(
    const u16* __restrict__ Qf, const u16* __restrict__ Kf, const u16* __restrict__ Vf,
    u16* __restrict__ Co) {
  __shared__ __align__(16) u16 Osw[32][64];  // epilogue transpose only
  const int bid = blockIdx.x;
  const int xcd = bid & 7, idx = bid >> 3;   // 4 bh per XCD for L2 locality
  const int bh = (xcd << 2) | (idx & 3);
  const int t = 63 - (idx >> 2);             // q 32-row tile, longest first
  const int b = bh >> 4, h = bh & 15;
  const int l = threadIdx.x;                 // single wave
  const int lq = l & 31, hi = l >> 5;
  const int qg = t * 32 + lq;
  const int n = (t >> 1) + 1;                // kv 64-tiles needed
  const float NEG = -3.0e38f;

  const u16* Qbase = Qf + (((size_t)(bh * 64 + t)) * 4) * 512 + l * 8;
  const u16* Kbase = Kf + ((size_t)(bh * 64) * 4) * 512 + l * 8;
  const u16* Vbase = Vf + ((size_t)(bh * 32) * 8) * 512 + l * 8;

  u16x8 qf[4];
#pragma unroll
  for (int ss = 0; ss < 4; ++ss) qf[ss] = *(const u16x8*)(Qbase + ss * 512);

  f32x16 o0, o1;
#pragma unroll
  for (int r = 0; r < 16; ++r) { o0[r] = 0.f; o1[r] = 0.f; }
  float m = NEG, ll = 0.f;

  u16x8 kl[4], kh[4], vl[4], vh[4];
#pragma unroll
  for (int ss = 0; ss < 4; ++ss) {           // prologue: K tile 0
    kl[ss] = *(const u16x8*)(Kbase + ss * 512);
    kh[ss] = *(const u16x8*)(Kbase + (4 + ss) * 512);
  }

  for (int j = 0; j < n; ++j) {
    const bool diag = (j == n - 1);
    const bool half2 = !(diag && !(t & 1));  // skip kv[32,64) when fully masked
    // V loads for this tile (consumed after softmax -> latency hidden)
    const u16* pv = Vbase + (size_t)j * 8 * 512;
#pragma unroll
    for (int kp = 0; kp < 4; ++kp) {
      vl[kp] = *(const u16x8*)(pv + kp * 512);
      vh[kp] = *(const u16x8*)(pv + (4 + kp) * 512);
    }
    // QK^T swapped: S^T[kv][q] += K[kv][d] * Q[q][d]
    f32x16 s0, s1;
#pragma unroll
    for (int r = 0; r < 16; ++r) { s0[r] = 0.f; s1[r] = 0.f; }
    __builtin_amdgcn_s_setprio(1);
    s0 = mfma32(kl[0], qf[0], s0);
    s0 = mfma32(kl[1], qf[1], s0);
    s0 = mfma32(kl[2], qf[2], s0);
    s0 = mfma32(kl[3], qf[3], s0);
    if (half2) {
      s1 = mfma32(kh[0], qf[0], s1);
      s1 = mfma32(kh[1], qf[1], s1);
      s1 = mfma32(kh[2], qf[2], s1);
      s1 = mfma32(kh[3], qf[3], s1);
    }
    __builtin_amdgcn_s_setprio(0);
    // prefetch next K tile (flies under softmax+PV)
    if (j + 1 < n) {
      const u16* pk = Kbase + (size_t)(j + 1) * 8 * 512;
#pragma unroll
      for (int ss = 0; ss < 4; ++ss) {
        kl[ss] = *(const u16x8*)(pk + ss * 512);
        kh[ss] = *(const u16x8*)(pk + (4 + ss) * 512);
      }
    }
    if (diag) {  // causal mask; kv row = (r&3)+8*(r>>2)+4*hi
      if (!(t & 1)) {
#pragma unroll
        for (int r = 0; r < 16; ++r) {
          int kv = j * 64 + (r & 3) + 8 * (r >> 2) + 4 * hi;
          if (kv > qg) s0[r] = NEG;
        }
      } else {
#pragma unroll
        for (int r = 0; r < 16; ++r) {
          int kv = j * 64 + 32 + (r & 3) + 8 * (r >> 2) + 4 * hi;
          if (kv > qg) s1[r] = NEG;
        }
      }
    }
    // online softmax in exp2 domain (lane pair l / l^32 share q column lq)
    float pm = NEG;
#pragma unroll
    for (int r = 0; r < 16; ++r) pm = fmaxf(pm, s0[r]);
    if (half2) {
#pragma unroll
      for (int r = 0; r < 16; ++r) pm = fmaxf(pm, s1[r]);
    }
    pm = fmaxf(pm, __shfl_xor(pm, 32));
    if (__any(pm > m + 8.0f)) {   // T13 defer-max (P bounded by 2^8)
      float mn = fmaxf(m, pm);
      float scl = exp2f(m - mn);
#pragma unroll
      for (int r = 0; r < 16; ++r) { o0[r] *= scl; o1[r] *= scl; }
      ll *= scl;
      m = mn;
    }
    float ps = 0.f;
#pragma unroll
    for (int r = 0; r < 16; ++r) { s0[r] = exp2f(s0[r] - m); ps += s0[r]; }
    if (half2) {
#pragma unroll
      for (int r = 0; r < 16; ++r) { s1[r] = exp2f(s1[r] - m); ps += s1[r]; }
    }
    ps += __shfl_xor(ps, 32);
    ll += ps;
    // T12: pack P into PV B-fragments
    u16x8 pf0, pf1, pf2, pf3;
    {
      unsigned w0, w1, w2, w3;
      pk_swap(s0[0], s0[1], s0[4], s0[5], w0, w2);
      pk_swap(s0[2], s0[3], s0[6], s0[7], w1, w3);
      pf0 = __builtin_bit_cast(u16x8, (u32x4){w0, w1, w2, w3});
      pk_swap(s0[8], s0[9], s0[12], s0[13], w0, w2);
      pk_swap(s0[10], s0[11], s0[14], s0[15], w1, w3);
      pf1 = __builtin_bit_cast(u16x8, (u32x4){w0, w1, w2, w3});
      if (half2) {
        pk_swap(s1[0], s1[1], s1[4], s1[5], w0, w2);
        pk_swap(s1[2], s1[3], s1[6], s1[7], w1, w3);
        pf2 = __builtin_bit_cast(u16x8, (u32x4){w0, w1, w2, w3});
        pk_swap(s1[8], s1[9], s1[12], s1[13], w0, w2);
        pk_swap(s1[10], s1[11], s1[14], s1[15], w1, w3);
        pf3 = __builtin_bit_cast(u16x8, (u32x4){w0, w1, w2, w3});
      }
    }
    // PV: O^T[e][q] += Vt[e][kv] * P[kv][q]
    __builtin_amdgcn_s_setprio(1);
    o0 = mfma32(vl[0], pf0, o0);
    o1 = mfma32(vh[0], pf0, o1);
    o0 = mfma32(vl[1], pf1, o0);
    o1 = mfma32(vh[1], pf1, o1);
    if (half2) {
      o0 = mfma32(vl[2], pf2, o0);
      o1 = mfma32(vh[2], pf2, o1);
      o0 = mfma32(vl[3], pf3, o0);
      o1 = mfma32(vh[3], pf3, o1);
    }
    __builtin_amdgcn_s_setprio(0);
  }

  // epilogue: normalize, transpose through LDS (single wave, no barrier), store
  float inv = 1.0f / ll;
#pragma unroll
  for (int r = 0; r < 16; ++r) {
    int drow = (r & 3) + 8 * (r >> 2) + 4 * hi;
    *(u16*)swzb(Osw, lq, drow * 2) = f2bf(o0[r] * inv);
    *(u16*)swzb(Osw, lq, (32 + drow) * 2) = f2bf(o1[r] * inv);
  }
  u16* dst = Co + ((size_t)(b * S_ + qg)) * EMB_ + h * HS_ + hi * 32;
#pragma unroll
  for (int k = 0; k < 4; ++k) {
    u16x8 vv = *swzp(Osw, lq, (hi * 32 + k * 8) * 2);
    *(u16x8*)(dst + k * 8) = vv;
  }
}

// ---------------- K3: out = concat @ Wo + bo (fp32 out), 64x128 tiles ----------------
__global__ __launch_bounds__(256) void k_outproj(
    const u16* __restrict__ Cc, const u16* __restrict__ Wot,
    const float* __restrict__ bo, float* __restrict__ out) {
  __shared__ __align__(16) u16 As[64][64];
  __shared__ __align__(16) u16 Bs[128][64];
  const int bid = blockIdx.x;
  const int xcd = bid & 7, sl = bid >> 3;   // sl 0..63
  const int mb = (xcd << 3) | (sl >> 3);    // 0..63
  const int nb = sl & 7;                    // 0..7
  const int t = threadIdx.x;
  const int lane = t & 63, wv = t >> 6;
  const int lq = lane & 15, lg = lane >> 4;
  const int wr = wv >> 1, wc = wv & 1;
  const int srA = t >> 2, scA = (t & 3) << 4;
  const int srB = t >> 1, scB = (t & 1) << 5;
  f32x4 acc[2][4];
#pragma unroll
  for (int mi = 0; mi < 2; ++mi)
#pragma unroll
    for (int ni = 0; ni < 4; ++ni) { f32x4 z = {0.f, 0.f, 0.f, 0.f}; acc[mi][ni] = z; }
  const u16* abase = Cc + ((size_t)(mb * 64 + srA)) * EMB_ + scA;
  const u16* bbase = Wot + ((size_t)(nb * 128 + srB)) * EMB_ + scB;
  u16x8 ar[2], br[4];
#pragma unroll
  for (int q = 0; q < 2; ++q) ar[q] = *(const u16x8*)(abase + q * 8);
#pragma unroll
  for (int q = 0; q < 4; ++q) br[q] = *(const u16x8*)(bbase + q * 8);
  for (int kt = 0; kt < 16; ++kt) {
    __syncthreads();
#pragma unroll
    for (int q = 0; q < 2; ++q) *swzp(As, srA, (scA + q * 8) * 2) = ar[q];
#pragma unroll
    for (int q = 0; q < 4; ++q) *swzp(Bs, srB, (scB + q * 8) * 2) = br[q];
    __syncthreads();
    if (kt < 15) {
#pragma unroll
      for (int q = 0; q < 2; ++q) ar[q] = *(const u16x8*)(abase + (kt + 1) * 64 + q * 8);
#pragma unroll
      for (int q = 0; q < 4; ++q) br[q] = *(const u16x8*)(bbase + (kt + 1) * 64 + q * 8);
    }
#pragma unroll
    for (int kf = 0; kf < 2; ++kf) {
      u16x8 af[2], bf[4];
#pragma unroll
      for (int mi = 0; mi < 2; ++mi)
        af[mi] = *swzp(As, wr * 32 + mi * 16 + lq, kf * 64 + lg * 16);
#pragma unroll
      for (int ni = 0; ni < 4; ++ni)
        bf[ni] = *swzp(Bs, wc * 64 + ni * 16 + lq, kf * 64 + lg * 16);
#pragma unroll
      for (int mi = 0; mi < 2; ++mi)
#pragma unroll
        for (int ni = 0; ni < 4; ++ni)
          acc[mi][ni] = mfma16(af[mi], bf[ni], acc[mi][ni]);
    }
  }
#pragma unroll
  for (int mi = 0; mi < 2; ++mi) {
#pragma unroll
    for (int ni = 0; ni < 4; ++ni) {
      int col = nb * 128 + wc * 64 + ni * 16 + lq;
      float bv = bo[col];
#pragma unroll
      for (int rr = 0; rr < 4; ++rr) {
        int row = mb * 64 + wr * 32 + mi * 16 + lg * 4 + rr;
        out[(size_t)row * EMB_ + col] = acc[mi][ni][rr] + bv;
      }
    }
  }
}

extern "C" void kernel_launch(void* const* d_in, const int* in_sizes, int n_in,
                              void* d_out, int out_size, void* d_ws, size_t ws_size,
                              hipStream_t stream) {
  const float* xk = (const float*)d_in[0];
  const float* xv = (const float*)d_in[1];
  const float* xq = (const float*)d_in[2];
  const float* Wk = (const float*)d_in[3];
  const float* Wv = (const float*)d_in[4];
  const float* Wq = (const float*)d_in[5];
  const float* Wo = (const float*)d_in[6];
  const float* bo = (const float*)d_in[7];
  float* out = (float*)d_out;
  char* ws = (char*)d_ws;
  const size_t MB8 = (size_t)8 * 1024 * 1024;
  u16* Qfw = (u16*)(ws);             // fragment-major Q (pre-scaled, exp2 domain)
  u16* Kfw = (u16*)(ws + MB8);       // fragment-major K
  u16* Vfw = (u16*)(ws + 2 * MB8);   // fragment-major V^T
  u16* Cw  = (u16*)(ws + 3 * MB8);   // concat [2][2048][1024]
  u16* Wot = (u16*)(ws + 4 * MB8);   // [1024][1024]

  k_transpose_wo<<<dim3(16, 16), 256, 0, stream>>>(Wo, Wot);
  k_proj<<<dim3(32, 32), 256, 0, stream>>>(xq, xk, xv, Wq, Wk, Wv, Qfw, Kfw, Vfw);
  k_attn<<<2048, 64, 0, stream>>>(Qfw, Kfw, Vfw, Cw);
  k_outproj<<<512, 256, 0, stream>>>(Cw, Wot, bo, out);
}

// Round 6
// 71.727 us; speedup vs baseline: 1.5011x; 1.2307x over previous
//
#include <hip/hip_runtime.h>
#include <hip/hip_bf16.h>
#include <cstdint>

typedef unsigned short u16;
typedef __bf16 bf16x8 __attribute__((ext_vector_type(8)));
typedef u16 u16x8 __attribute__((ext_vector_type(8)));
typedef unsigned u32x4 __attribute__((ext_vector_type(4)));
typedef float f32x4 __attribute__((ext_vector_type(4)));
typedef float f32x16 __attribute__((ext_vector_type(16)));

#define B_ 2
#define S_ 2048
#define H_ 16
#define HS_ 64
#define EMB_ 1024
#define QSCALE 0.022097086912079608f  /* 1/sqrt(2048) */
#define LOG2E  1.4426950408889634f    /* folded into Q so softmax uses exp2 */

static __device__ __forceinline__ u16 f2bf(float f) {
  unsigned int u = __float_as_uint(f);
  u += 0x7fffu + ((u >> 16) & 1u);   // RNE
  return (u16)(u >> 16);
}

// single-instruction 2^x (library exp2f adds ~10 insts of edge handling)
static __device__ __forceinline__ float ex2(float x) {
#if __has_builtin(__builtin_amdgcn_exp2f)
  return __builtin_amdgcn_exp2f(x);
#else
  float r; asm("v_exp_f32 %0, %1" : "=v"(r) : "v"(x)); return r;
#endif
}

static __device__ __forceinline__ f32x4 mfma16(u16x8 a, u16x8 b, f32x4 c) {
  return __builtin_amdgcn_mfma_f32_16x16x32_bf16(
      __builtin_bit_cast(bf16x8, a), __builtin_bit_cast(bf16x8, b), c, 0, 0, 0);
}
static __device__ __forceinline__ f32x16 mfma32(u16x8 a, u16x8 b, f32x16 c) {
  return __builtin_amdgcn_mfma_f32_32x32x16_bf16(
      __builtin_bit_cast(bf16x8, a), __builtin_bit_cast(bf16x8, b), c, 0, 0, 0);
}

// XOR-swizzled address into a tile with 128B row stride (LDS bank-conflict fix).
static __device__ __forceinline__ char* swzb(void* base, int row, int colbyte) {
  return (char*)base + ((row * 128 + colbyte) ^ ((row & 7) << 4));
}
static __device__ __forceinline__ u16x8* swzp(void* base, int row, int colbyte) {
  return (u16x8*)swzb(base, row, colbyte);
}

// cvt_pk two f32 pairs to packed bf16 words, then permlane32_swap (T12).
static __device__ __forceinline__ void pk_swap(float a0, float a1, float b0, float b1,
                                               unsigned& x, unsigned& y) {
  unsigned A, Bv;
  asm("v_cvt_pk_bf16_f32 %0, %1, %2" : "=v"(A) : "v"(a0), "v"(a1));
  asm("v_cvt_pk_bf16_f32 %0, %1, %2" : "=v"(Bv) : "v"(b0), "v"(b1));
  asm("v_permlane32_swap_b32 %0, %1" : "+v"(A), "+v"(Bv));
  x = A; y = Bv;
}

// ---------------- K0: Wo[k][n] fp32 -> Wot[n][k] bf16 ----------------
__global__ __launch_bounds__(256) void k_transpose_wo(const float* __restrict__ Wo,
                                                      u16* __restrict__ Wot) {
  __shared__ __align__(16) u16 T[64][72];
  const int kb = blockIdx.y * 64, nb = blockIdx.x * 64;
  const int r = threadIdx.x >> 2;
  const int c0 = (threadIdx.x & 3) << 4;
  const float* src = Wo + (size_t)(kb + r) * EMB_ + nb + c0;
#pragma unroll
  for (int i = 0; i < 16; i += 4) {
    float4 f = *(const float4*)(src + i);
    T[c0 + i + 0][r] = f2bf(f.x);
    T[c0 + i + 1][r] = f2bf(f.y);
    T[c0 + i + 2][r] = f2bf(f.z);
    T[c0 + i + 3][r] = f2bf(f.w);
  }
  __syncthreads();
  u16* dst = Wot + (size_t)(nb + r) * EMB_ + kb + c0;
  *(u16x8*)(dst)     = *(const u16x8*)&T[r][c0];
  *(u16x8*)(dst + 8) = *(const u16x8*)&T[r][c0 + 8];
}

// ---------------- K1: projections -> FRAGMENT-MAJOR layouts ----------------
// Qf: [bh][t:64][slice:4][lane:64][8]   = Q[t*32+(l&31)][slice*16+(l>>5)*8+j] * QSCALE*LOG2E
// Kf: [bh][tau:64][slice:4][lane:64][8] = K[tau*32+(l&31)][slice*16+(l>>5)*8+j]
// Vf: [bh][j:32][eta:2][kap:4][lane:64][8] = Vt[eta*32+(l&31)][j*64+kap*16+(l>>5)*8+jj]
__global__ __launch_bounds__(256) void k_proj(
    const float* __restrict__ xq, const float* __restrict__ xk, const float* __restrict__ xv,
    const float* __restrict__ Wq, const float* __restrict__ Wk, const float* __restrict__ Wv,
    u16* __restrict__ Qf, u16* __restrict__ Kf, u16* __restrict__ Vf) {
  __shared__ __align__(16) u16 Xb[64][64];
  __shared__ __align__(16) u16 Wb[64][64];   // Wb[e][d] = W[d][e]
  __shared__ __align__(16) u16 Tt[64][64];
  const int sb = blockIdx.x;   // s-block 0..31
  const int bh = blockIdx.y;   // 0..31
  const int b = bh >> 4, h = bh & 15;
  const int t = threadIdx.x;
  const int r = t >> 2, c0 = (t & 3) << 4;
  const int lane = t & 63, wv = t >> 6;
  const int lq = lane & 15, lg = lane >> 4;
  const int l31 = lane & 31, hi = lane >> 5;
  const float* xs[3] = {xq, xk, xv};
  const float* ws3[3] = {Wq, Wk, Wv};

  for (int tn = 0; tn < 3; ++tn) {
    __syncthreads();
    const float* src = xs[tn] + ((size_t)(b * S_ + sb * 64 + r)) * HS_ + c0;
#pragma unroll
    for (int i = 0; i < 16; i += 8) {
      float4 fa = *(const float4*)(src + i);
      float4 fb = *(const float4*)(src + i + 4);
      u16x8 v = {f2bf(fa.x), f2bf(fa.y), f2bf(fa.z), f2bf(fa.w),
                 f2bf(fb.x), f2bf(fb.y), f2bf(fb.z), f2bf(fb.w)};
      *swzp(Xb, r, (c0 + i) * 2) = v;
    }
    const float* wsp = ws3[tn] + ((size_t)(h * HS_ + r)) * HS_ + c0;
#pragma unroll
    for (int i = 0; i < 16; i += 4) {
      float4 f = *(const float4*)(wsp + i);
      *(u16*)swzb(Wb, c0 + i + 0, r * 2) = f2bf(f.x);
      *(u16*)swzb(Wb, c0 + i + 1, r * 2) = f2bf(f.y);
      *(u16*)swzb(Wb, c0 + i + 2, r * 2) = f2bf(f.z);
      *(u16*)swzb(Wb, c0 + i + 3, r * 2) = f2bf(f.w);
    }
    __syncthreads();
    if (tn < 2) {
      u16x8 a0 = *swzp(Xb, wv * 16 + lq, lg * 16);
      u16x8 a1 = *swzp(Xb, wv * 16 + lq, 64 + lg * 16);
      const float osc = (tn == 0) ? (QSCALE * LOG2E) : 1.0f;
#pragma unroll
      for (int et = 0; et < 4; ++et) {
        u16x8 b0 = *swzp(Wb, et * 16 + lq, lg * 16);
        u16x8 b1 = *swzp(Wb, et * 16 + lq, 64 + lg * 16);
        f32x4 acc = {0.f, 0.f, 0.f, 0.f};
        acc = mfma16(a0, b0, acc);
        acc = mfma16(a1, b1, acc);
#pragma unroll
        for (int rr = 0; rr < 4; ++rr)
          *(u16*)swzb(Tt, wv * 16 + lg * 4 + rr, (et * 16 + lq) * 2) = f2bf(acc[rr] * osc);
      }
    } else {
      u16x8 xb0 = *swzp(Xb, wv * 16 + lq, lg * 16);
      u16x8 xb1 = *swzp(Xb, wv * 16 + lq, 64 + lg * 16);
#pragma unroll
      for (int et = 0; et < 4; ++et) {
        u16x8 a0 = *swzp(Wb, et * 16 + lq, lg * 16);
        u16x8 a1 = *swzp(Wb, et * 16 + lq, 64 + lg * 16);
        f32x4 acc = {0.f, 0.f, 0.f, 0.f};
        acc = mfma16(a0, xb0, acc);
        acc = mfma16(a1, xb1, acc);
#pragma unroll
        for (int rr = 0; rr < 4; ++rr)
          *(u16*)swzb(Tt, et * 16 + lg * 4 + rr, (wv * 16 + lq) * 2) = f2bf(acc[rr]);
      }
    }
    __syncthreads();
    if (tn < 2) {
      u16* dst = (tn == 0) ? Qf : Kf;
#pragma unroll
      for (int tl = 0; tl < 2; ++tl) {
        u16x8 v = *swzp(Tt, tl * 32 + l31, wv * 32 + hi * 16);
        size_t off = (((size_t)(bh * 64 + sb * 2 + tl)) * 4 + wv) * 512 + lane * 8;
        *(u16x8*)(dst + off) = v;
      }
    } else {
#pragma unroll
      for (int eta = 0; eta < 2; ++eta) {
        u16x8 v = *swzp(Tt, eta * 32 + l31, wv * 32 + hi * 16);
        size_t off = ((((size_t)(bh * 32 + sb)) * 2 + eta) * 4 + wv) * 512 + lane * 8;
        *(u16x8*)(Vf + off) = v;
      }
    }
  }
}

// ---------------- K2: causal flash attention, 2-wave kv-split, no-max softmax ----
// Block (128 thr) = one 32-row q-tile; wave0 kv [0,mid), wave1 kv [mid,n) with the
// diagonal tile PEELED. No cross-lane ops / branches / barriers in the hot loop.
// QK accumulator init = -16 gives a free static max (P = 2^(s-16)); kv-split
// partials are then pure sums -> merge is 33 adds via LDS.
__global__ __launch_bounds__(128) void k_attn(
    const u16* __restrict__ Qf, const u16* __restrict__ Kf, const u16* __restrict__ Vf,
    u16* __restrict__ Co) {
  __shared__ float Xch[64][33];              // wave1 partials: o0[16], o1[16], ll
  __shared__ __align__(16) u16 Osw[32][64];  // wave0 epilogue transpose
  const int bid = blockIdx.x;
  const int xcd = bid & 7, idx = bid >> 3;   // 4 bh per XCD for L2 locality
  const int bh = (xcd << 2) | (idx & 3);
  const int t = 63 - (idx >> 2);             // q 32-row tile, longest first
  const int b = bh >> 4, h = bh & 15;
  const int w = threadIdx.x >> 6;
  const int l = threadIdx.x & 63;
  const int lq = l & 31, hi = l >> 5;
  const int qg = t * 32 + lq;
  const int n = (t >> 1) + 1;                // kv 64-tiles needed
  const int mid = n >> 1;
  const int jbeg = w ? mid : 0;
  const int jhot = w ? (n - 1) : mid;        // diag (j = n-1) peeled to wave1
  const float NEG = -3.0e38f;

  const u16* Qbase = Qf + (((size_t)(bh * 64 + t)) * 4) * 512 + l * 8;
  const u16* Kbase = Kf + ((size_t)(bh * 64) * 4) * 512 + l * 8;
  const u16* Vbase = Vf + ((size_t)(bh * 32) * 8) * 512 + l * 8;

  u16x8 qf[4];
#pragma unroll
  for (int ss = 0; ss < 4; ++ss) qf[ss] = *(const u16x8*)(Qbase + ss * 512);

  f32x16 o0, o1;
#pragma unroll
  for (int r = 0; r < 16; ++r) { o0[r] = 0.f; o1[r] = 0.f; }
  float ll = 0.f;

  u16x8 kl[4], kh[4], vl[4], vh[4];
  {
    const u16* p = Kbase + (size_t)jbeg * 8 * 512;   // prologue K
#pragma unroll
    for (int ss = 0; ss < 4; ++ss) {
      kl[ss] = *(const u16x8*)(p + ss * 512);
      kh[ss] = *(const u16x8*)(p + (4 + ss) * 512);
    }
  }

  for (int j = jbeg; j < jhot; ++j) {
    const u16* pv = Vbase + (size_t)j * 8 * 512;
#pragma unroll
    for (int kp = 0; kp < 4; ++kp) {
      vl[kp] = *(const u16x8*)(pv + kp * 512);
      vh[kp] = *(const u16x8*)(pv + (4 + kp) * 512);
    }
    f32x16 s0, s1;
#pragma unroll
    for (int r = 0; r < 16; ++r) { s0[r] = -16.f; s1[r] = -16.f; }
    __builtin_amdgcn_s_setprio(1);
    s0 = mfma32(kl[0], qf[0], s0);
    s0 = mfma32(kl[1], qf[1], s0);
    s0 = mfma32(kl[2], qf[2], s0);
    s0 = mfma32(kl[3], qf[3], s0);
    s1 = mfma32(kh[0], qf[0], s1);
    s1 = mfma32(kh[1], qf[1], s1);
    s1 = mfma32(kh[2], qf[2], s1);
    s1 = mfma32(kh[3], qf[3], s1);
    __builtin_amdgcn_s_setprio(0);
    {  // prefetch next K tile (j+1 <= n-1 always valid)
      const u16* pk = Kbase + (size_t)(j + 1) * 8 * 512;
#pragma unroll
      for (int ss = 0; ss < 4; ++ss) {
        kl[ss] = *(const u16x8*)(pk + ss * 512);
        kh[ss] = *(const u16x8*)(pk + (4 + ss) * 512);
      }
    }
    float ps = 0.f;
#pragma unroll
    for (int r = 0; r < 16; ++r) { s0[r] = ex2(s0[r]); ps += s0[r]; }
#pragma unroll
    for (int r = 0; r < 16; ++r) { s1[r] = ex2(s1[r]); ps += s1[r]; }
    ll += ps;
    u16x8 pf0, pf1, pf2, pf3;
    {
      unsigned w0, w1, w2, w3;
      pk_swap(s0[0], s0[1], s0[4], s0[5], w0, w2);
      pk_swap(s0[2], s0[3], s0[6], s0[7], w1, w3);
      pf0 = __builtin_bit_cast(u16x8, (u32x4){w0, w1, w2, w3});
      pk_swap(s0[8], s0[9], s0[12], s0[13], w0, w2);
      pk_swap(s0[10], s0[11], s0[14], s0[15], w1, w3);
      pf1 = __builtin_bit_cast(u16x8, (u32x4){w0, w1, w2, w3});
      pk_swap(s1[0], s1[1], s1[4], s1[5], w0, w2);
      pk_swap(s1[2], s1[3], s1[6], s1[7], w1, w3);
      pf2 = __builtin_bit_cast(u16x8, (u32x4){w0, w1, w2, w3});
      pk_swap(s1[8], s1[9], s1[12], s1[13], w0, w2);
      pk_swap(s1[10], s1[11], s1[14], s1[15], w1, w3);
      pf3 = __builtin_bit_cast(u16x8, (u32x4){w0, w1, w2, w3});
    }
    __builtin_amdgcn_s_setprio(1);
    o0 = mfma32(vl[0], pf0, o0);
    o1 = mfma32(vh[0], pf0, o1);
    o0 = mfma32(vl[1], pf1, o0);
    o1 = mfma32(vh[1], pf1, o1);
    o0 = mfma32(vl[2], pf2, o0);
    o1 = mfma32(vh[2], pf2, o1);
    o0 = mfma32(vl[3], pf3, o0);
    o1 = mfma32(vh[3], pf3, o1);
    __builtin_amdgcn_s_setprio(0);
  }

  if (w) {  // peeled diagonal tile j = n-1 (kl/kh already hold K[n-1])
    const int j = n - 1;
    const u16* pv = Vbase + (size_t)j * 8 * 512;
#pragma unroll
    for (int kp = 0; kp < 4; ++kp) {
      vl[kp] = *(const u16x8*)(pv + kp * 512);
      vh[kp] = *(const u16x8*)(pv + (4 + kp) * 512);
    }
    f32x16 s0, s1;
#pragma unroll
    for (int r = 0; r < 16; ++r) { s0[r] = -16.f; s1[r] = -16.f; }
    s0 = mfma32(kl[0], qf[0], s0);
    s0 = mfma32(kl[1], qf[1], s0);
    s0 = mfma32(kl[2], qf[2], s0);
    s0 = mfma32(kl[3], qf[3], s0);
    if (t & 1) {
      s1 = mfma32(kh[0], qf[0], s1);
      s1 = mfma32(kh[1], qf[1], s1);
      s1 = mfma32(kh[2], qf[2], s1);
      s1 = mfma32(kh[3], qf[3], s1);
    }
    if (t & 1) {  // q rows in upper half: s0 fully unmasked, mask s1
#pragma unroll
      for (int r = 0; r < 16; ++r) {
        int kv = j * 64 + 32 + (r & 3) + 8 * (r >> 2) + 4 * hi;
        if (kv > qg) s1[r] = NEG;
      }
    } else {      // q rows in lower half: mask s0, skip s1 entirely
#pragma unroll
      for (int r = 0; r < 16; ++r) {
        int kv = j * 64 + (r & 3) + 8 * (r >> 2) + 4 * hi;
        if (kv > qg) s0[r] = NEG;
      }
    }
    float ps = 0.f;
#pragma unroll
    for (int r = 0; r < 16; ++r) { s0[r] = ex2(s0[r]); ps += s0[r]; }
    if (t & 1) {
#pragma unroll
      for (int r = 0; r < 16; ++r) { s1[r] = ex2(s1[r]); ps += s1[r]; }
    }
    ll += ps;
    u16x8 pf0, pf1, pf2, pf3;
    {
      unsigned w0, w1, w2, w3;
      pk_swap(s0[0], s0[1], s0[4], s0[5], w0, w2);
      pk_swap(s0[2], s0[3], s0[6], s0[7], w1, w3);
      pf0 = __builtin_bit_cast(u16x8, (u32x4){w0, w1, w2, w3});
      pk_swap(s0[8], s0[9], s0[12], s0[13], w0, w2);
      pk_swap(s0[10], s0[11], s0[14], s0[15], w1, w3);
      pf1 = __builtin_bit_cast(u16x8, (u32x4){w0, w1, w2, w3});
      if (t & 1) {
        pk_swap(s1[0], s1[1], s1[4], s1[5], w0, w2);
        pk_swap(s1[2], s1[3], s1[6], s1[7], w1, w3);
        pf2 = __builtin_bit_cast(u16x8, (u32x4){w0, w1, w2, w3});
        pk_swap(s1[8], s1[9], s1[12], s1[13], w0, w2);
        pk_swap(s1[10], s1[11], s1[14], s1[15], w1, w3);
        pf3 = __builtin_bit_cast(u16x8, (u32x4){w0, w1, w2, w3});
      }
    }
    o0 = mfma32(vl[0], pf0, o0);
    o1 = mfma32(vh[0], pf0, o1);
    o0 = mfma32(vl[1], pf1, o0);
    o1 = mfma32(vh[1], pf1, o1);
    if (t & 1) {
      o0 = mfma32(vl[2], pf2, o0);
      o1 = mfma32(vh[2], pf2, o1);
      o0 = mfma32(vl[3], pf3, o0);
      o1 = mfma32(vh[3], pf3, o1);
    }
    // publish wave1 partials (pure sums — no rescale needed)
#pragma unroll
    for (int r = 0; r < 16; ++r) { Xch[l][r] = o0[r]; Xch[l][16 + r] = o1[r]; }
    Xch[l][32] = ll;
  }
  __syncthreads();
  if (w == 0) {
#pragma unroll
    for (int r = 0; r < 16; ++r) { o0[r] += Xch[l][r]; o1[r] += Xch[l][16 + r]; }
    ll += Xch[l][32];
    ll += __shfl_xor(ll, 32);
    float inv = 1.0f / ll;
#pragma unroll
    for (int r = 0; r < 16; ++r) {
      int drow = (r & 3) + 8 * (r >> 2) + 4 * hi;
      *(u16*)swzb(Osw, lq, drow * 2) = f2bf(o0[r] * inv);
      *(u16*)swzb(Osw, lq, (32 + drow) * 2) = f2bf(o1[r] * inv);
    }
    u16* dst = Co + ((size_t)(b * S_ + qg)) * EMB_ + h * HS_ + hi * 32;
#pragma unroll
    for (int k = 0; k < 4; ++k) {
      u16x8 vv = *swzp(Osw, lq, (hi * 32 + k * 8) * 2);
      *(u16x8*)(dst + k * 8) = vv;
    }
  }
}

// ---------------- K3: out = concat @ Wo + bo (fp32 out), 64x128 tiles ----------------
__global__ __launch_bounds__(256) void k_outproj(
    const u16* __restrict__ Cc, const u16* __restrict__ Wot,
    const float* __restrict__ bo, float* __restrict__ out) {
  __shared__ __align__(16) u16 As[64][64];
  __shared__ __align__(16) u16 Bs[128][64];
  const int bid = blockIdx.x;
  const int xcd = bid & 7, sl = bid >> 3;
  const int mb = (xcd << 3) | (sl >> 3);
  const int nb = sl & 7;
  const int t = threadIdx.x;
  const int lane = t & 63, wv = t >> 6;
  const int lq = lane & 15, lg = lane >> 4;
  const int wr = wv >> 1, wc = wv & 1;
  const int srA = t >> 2, scA = (t & 3) << 4;
  const int srB = t >> 1, scB = (t & 1) << 5;
  f32x4 acc[2][4];
#pragma unroll
  for (int mi = 0; mi < 2; ++mi)
#pragma unroll
    for (int ni = 0; ni < 4; ++ni) { f32x4 z = {0.f, 0.f, 0.f, 0.f}; acc[mi][ni] = z; }
  const u16* abase = Cc + ((size_t)(mb * 64 + srA)) * EMB_ + scA;
  const u16* bbase = Wot + ((size_t)(nb * 128 + srB)) * EMB_ + scB;
  u16x8 ar[2], br[4];
#pragma unroll
  for (int q = 0; q < 2; ++q) ar[q] = *(const u16x8*)(abase + q * 8);
#pragma unroll
  for (int q = 0; q < 4; ++q) br[q] = *(const u16x8*)(bbase + q * 8);
  for (int kt = 0; kt < 16; ++kt) {
    __syncthreads();
#pragma unroll
    for (int q = 0; q < 2; ++q) *swzp(As, srA, (scA + q * 8) * 2) = ar[q];
#pragma unroll
    for (int q = 0; q < 4; ++q) *swzp(Bs, srB, (scB + q * 8) * 2) = br[q];
    __syncthreads();
    if (kt < 15) {
#pragma unroll
      for (int q = 0; q < 2; ++q) ar[q] = *(const u16x8*)(abase + (kt + 1) * 64 + q * 8);
#pragma unroll
      for (int q = 0; q < 4; ++q) br[q] = *(const u16x8*)(bbase + (kt + 1) * 64 + q * 8);
    }
#pragma unroll
    for (int kf = 0; kf < 2; ++kf) {
      u16x8 af[2], bf[4];
#pragma unroll
      for (int mi = 0; mi < 2; ++mi)
        af[mi] = *swzp(As, wr * 32 + mi * 16 + lq, kf * 64 + lg * 16);
#pragma unroll
      for (int ni = 0; ni < 4; ++ni)
        bf[ni] = *swzp(Bs, wc * 64 + ni * 16 + lq, kf * 64 + lg * 16);
#pragma unroll
      for (int mi = 0; mi < 2; ++mi)
#pragma unroll
        for (int ni = 0; ni < 4; ++ni)
          acc[mi][ni] = mfma16(af[mi], bf[ni], acc[mi][ni]);
    }
  }
#pragma unroll
  for (int mi = 0; mi < 2; ++mi) {
#pragma unroll
    for (int ni = 0; ni < 4; ++ni) {
      int col = nb * 128 + wc * 64 + ni * 16 + lq;
      float bv = bo[col];
#pragma unroll
      for (int rr = 0; rr < 4; ++rr) {
        int row = mb * 64 + wr * 32 + mi * 16 + lg * 4 + rr;
        out[(size_t)row * EMB_ + col] = acc[mi][ni][rr] + bv;
      }
    }
  }
}

extern "C" void kernel_launch(void* const* d_in, const int* in_sizes, int n_in,
                              void* d_out, int out_size, void* d_ws, size_t ws_size,
                              hipStream_t stream) {
  const float* xk = (const float*)d_in[0];
  const float* xv = (const float*)d_in[1];
  const float* xq = (const float*)d_in[2];
  const float* Wk = (const float*)d_in[3];
  const float* Wv = (const float*)d_in[4];
  const float* Wq = (const float*)d_in[5];
  const float* Wo = (const float*)d_in[6];
  const float* bo = (const float*)d_in[7];
  float* out = (float*)d_out;
  char* ws = (char*)d_ws;
  const size_t MB8 = (size_t)8 * 1024 * 1024;
  u16* Qfw = (u16*)(ws);             // fragment-major Q (pre-scaled, exp2 domain)
  u16* Kfw = (u16*)(ws + MB8);       // fragment-major K
  u16* Vfw = (u16*)(ws + 2 * MB8);   // fragment-major V^T
  u16* Cw  = (u16*)(ws + 3 * MB8);   // concat [2][2048][1024]
  u16* Wot = (u16*)(ws + 4 * MB8);   // [1024][1024]

  k_transpose_wo<<<dim3(16, 16), 256, 0, stream>>>(Wo, Wot);
  k_proj<<<dim3(32, 32), 256, 0, stream>>>(xq, xk, xv, Wq, Wk, Wv, Qfw, Kfw, Vfw);
  k_attn<<<2048, 128, 0, stream>>>(Qfw, Kfw, Vfw, Cw);
  k_outproj<<<512, 256, 0, stream>>>(Cw, Wot, bo, out);
}

// Round 7
// 65.342 us; speedup vs baseline: 1.6478x; 1.0977x over previous
//
#include <hip/hip_runtime.h>
#include <hip/hip_bf16.h>
#include <cstdint>

typedef unsigned short u16;
typedef __bf16 bf16x8 __attribute__((ext_vector_type(8)));
typedef u16 u16x8 __attribute__((ext_vector_type(8)));
typedef unsigned u32x4 __attribute__((ext_vector_type(4)));
typedef float f32x4 __attribute__((ext_vector_type(4)));
typedef float f32x16 __attribute__((ext_vector_type(16)));

#define B_ 2
#define S_ 2048
#define H_ 16
#define HS_ 64
#define EMB_ 1024
#define QSCALE 0.022097086912079608f  /* 1/sqrt(2048) */
#define LOG2E  1.4426950408889634f    /* folded into Q so softmax uses exp2 */

static __device__ __forceinline__ u16 f2bf(float f) {
  unsigned int u = __float_as_uint(f);
  u += 0x7fffu + ((u >> 16) & 1u);   // RNE
  return (u16)(u >> 16);
}

// single-instruction 2^x
static __device__ __forceinline__ float ex2(float x) {
#if __has_builtin(__builtin_amdgcn_exp2f)
  return __builtin_amdgcn_exp2f(x);
#else
  float r; asm("v_exp_f32 %0, %1" : "=v"(r) : "v"(x)); return r;
#endif
}

// depth-4 tree sum of 16 floats (avoids a 16-deep dependent add chain)
static __device__ __forceinline__ float tsum16(const f32x16& s) {
  float a0 = s[0] + s[1],  a1 = s[2] + s[3];
  float a2 = s[4] + s[5],  a3 = s[6] + s[7];
  float a4 = s[8] + s[9],  a5 = s[10] + s[11];
  float a6 = s[12] + s[13], a7 = s[14] + s[15];
  a0 += a1; a2 += a3; a4 += a5; a6 += a7;
  a0 += a2; a4 += a6;
  return a0 + a4;
}

static __device__ __forceinline__ f32x4 mfma16(u16x8 a, u16x8 b, f32x4 c) {
  return __builtin_amdgcn_mfma_f32_16x16x32_bf16(
      __builtin_bit_cast(bf16x8, a), __builtin_bit_cast(bf16x8, b), c, 0, 0, 0);
}
static __device__ __forceinline__ f32x16 mfma32(u16x8 a, u16x8 b, f32x16 c) {
  return __builtin_amdgcn_mfma_f32_32x32x16_bf16(
      __builtin_bit_cast(bf16x8, a), __builtin_bit_cast(bf16x8, b), c, 0, 0, 0);
}

// XOR-swizzled address into a tile with 128B row stride (LDS bank-conflict fix).
static __device__ __forceinline__ char* swzb(void* base, int row, int colbyte) {
  return (char*)base + ((row * 128 + colbyte) ^ ((row & 7) << 4));
}
static __device__ __forceinline__ u16x8* swzp(void* base, int row, int colbyte) {
  return (u16x8*)swzb(base, row, colbyte);
}

// cvt_pk two f32 pairs to packed bf16 words, then permlane32_swap (T12).
static __device__ __forceinline__ void pk_swap(float a0, float a1, float b0, float b1,
                                               unsigned& x, unsigned& y) {
  unsigned A, Bv;
  asm("v_cvt_pk_bf16_f32 %0, %1, %2" : "=v"(A) : "v"(a0), "v"(a1));
  asm("v_cvt_pk_bf16_f32 %0, %1, %2" : "=v"(Bv) : "v"(b0), "v"(b1));
  asm("v_permlane32_swap_b32 %0, %1" : "+v"(A), "+v"(Bv));
  x = A; y = Bv;
}

// ---------------- K0: Wo[k][n] fp32 -> Wot[n][k] bf16 ----------------
__global__ __launch_bounds__(256) void k_transpose_wo(const float* __restrict__ Wo,
                                                      u16* __restrict__ Wot) {
  __shared__ __align__(16) u16 T[64][72];
  const int kb = blockIdx.y * 64, nb = blockIdx.x * 64;
  const int r = threadIdx.x >> 2;
  const int c0 = (threadIdx.x & 3) << 4;
  const float* src = Wo + (size_t)(kb + r) * EMB_ + nb + c0;
#pragma unroll
  for (int i = 0; i < 16; i += 4) {
    float4 f = *(const float4*)(src + i);
    T[c0 + i + 0][r] = f2bf(f.x);
    T[c0 + i + 1][r] = f2bf(f.y);
    T[c0 + i + 2][r] = f2bf(f.z);
    T[c0 + i + 3][r] = f2bf(f.w);
  }
  __syncthreads();
  u16* dst = Wot + (size_t)(nb + r) * EMB_ + kb + c0;
  *(u16x8*)(dst)     = *(const u16x8*)&T[r][c0];
  *(u16x8*)(dst + 8) = *(const u16x8*)&T[r][c0 + 8];
}

// ---------------- K1: projections -> FRAGMENT-MAJOR layouts (tn = blockIdx.z) ----
// Qf: [bh][t:64][slice:4][lane:64][8]   = Q[t*32+(l&31)][slice*16+(l>>5)*8+j] * QSCALE*LOG2E
// Kf: [bh][tau:64][slice:4][lane:64][8] = K[tau*32+(l&31)][slice*16+(l>>5)*8+j]
// Vf: [bh][j:32][eta:2][kap:4][lane:64][8] = Vt[eta*32+(l&31)][j*64+kap*16+(l>>5)*8+jj]
__global__ __launch_bounds__(256) void k_proj(
    const float* __restrict__ xq, const float* __restrict__ xk, const float* __restrict__ xv,
    const float* __restrict__ Wq, const float* __restrict__ Wk, const float* __restrict__ Wv,
    u16* __restrict__ Qf, u16* __restrict__ Kf, u16* __restrict__ Vf) {
  __shared__ __align__(16) u16 Xb[64][64];
  __shared__ __align__(16) u16 Wb[64][64];   // Wb[e][d] = W[d][e]
  __shared__ __align__(16) u16 Tt[64][64];
  const int sb = blockIdx.x;   // s-block 0..31
  const int bh = blockIdx.y;   // 0..31
  const int tn = blockIdx.z;   // 0=Q, 1=K, 2=V
  const int b = bh >> 4, h = bh & 15;
  const int t = threadIdx.x;
  const int r = t >> 2, c0 = (t & 3) << 4;
  const int lane = t & 63, wv = t >> 6;
  const int lq = lane & 15, lg = lane >> 4;
  const int l31 = lane & 31, hi = lane >> 5;
  const float* xs = (tn == 0) ? xq : (tn == 1) ? xk : xv;
  const float* wsp3 = (tn == 0) ? Wq : (tn == 1) ? Wk : Wv;

  const float* src = xs + ((size_t)(b * S_ + sb * 64 + r)) * HS_ + c0;
#pragma unroll
  for (int i = 0; i < 16; i += 8) {
    float4 fa = *(const float4*)(src + i);
    float4 fb = *(const float4*)(src + i + 4);
    u16x8 v = {f2bf(fa.x), f2bf(fa.y), f2bf(fa.z), f2bf(fa.w),
               f2bf(fb.x), f2bf(fb.y), f2bf(fb.z), f2bf(fb.w)};
    *swzp(Xb, r, (c0 + i) * 2) = v;
  }
  const float* wsp = wsp3 + ((size_t)(h * HS_ + r)) * HS_ + c0;
#pragma unroll
  for (int i = 0; i < 16; i += 4) {
    float4 f = *(const float4*)(wsp + i);
    *(u16*)swzb(Wb, c0 + i + 0, r * 2) = f2bf(f.x);
    *(u16*)swzb(Wb, c0 + i + 1, r * 2) = f2bf(f.y);
    *(u16*)swzb(Wb, c0 + i + 2, r * 2) = f2bf(f.z);
    *(u16*)swzb(Wb, c0 + i + 3, r * 2) = f2bf(f.w);
  }
  __syncthreads();
  if (tn < 2) {
    u16x8 a0 = *swzp(Xb, wv * 16 + lq, lg * 16);
    u16x8 a1 = *swzp(Xb, wv * 16 + lq, 64 + lg * 16);
    const float osc = (tn == 0) ? (QSCALE * LOG2E) : 1.0f;
#pragma unroll
    for (int et = 0; et < 4; ++et) {
      u16x8 b0 = *swzp(Wb, et * 16 + lq, lg * 16);
      u16x8 b1 = *swzp(Wb, et * 16 + lq, 64 + lg * 16);
      f32x4 acc = {0.f, 0.f, 0.f, 0.f};
      acc = mfma16(a0, b0, acc);
      acc = mfma16(a1, b1, acc);
#pragma unroll
      for (int rr = 0; rr < 4; ++rr)
        *(u16*)swzb(Tt, wv * 16 + lg * 4 + rr, (et * 16 + lq) * 2) = f2bf(acc[rr] * osc);
    }
  } else {
    u16x8 xb0 = *swzp(Xb, wv * 16 + lq, lg * 16);
    u16x8 xb1 = *swzp(Xb, wv * 16 + lq, 64 + lg * 16);
#pragma unroll
    for (int et = 0; et < 4; ++et) {
      u16x8 a0 = *swzp(Wb, et * 16 + lq, lg * 16);
      u16x8 a1 = *swzp(Wb, et * 16 + lq, 64 + lg * 16);
      f32x4 acc = {0.f, 0.f, 0.f, 0.f};
      acc = mfma16(a0, xb0, acc);
      acc = mfma16(a1, xb1, acc);
#pragma unroll
      for (int rr = 0; rr < 4; ++rr)
        *(u16*)swzb(Tt, et * 16 + lg * 4 + rr, (wv * 16 + lq) * 2) = f2bf(acc[rr]);
    }
  }
  __syncthreads();
  if (tn < 2) {
    u16* dst = (tn == 0) ? Qf : Kf;
#pragma unroll
    for (int tl = 0; tl < 2; ++tl) {
      u16x8 v = *swzp(Tt, tl * 32 + l31, wv * 32 + hi * 16);
      size_t off = (((size_t)(bh * 64 + sb * 2 + tl)) * 4 + wv) * 512 + lane * 8;
      *(u16x8*)(dst + off) = v;
    }
  } else {
#pragma unroll
    for (int eta = 0; eta < 2; ++eta) {
      u16x8 v = *swzp(Tt, eta * 32 + l31, wv * 32 + hi * 16);
      size_t off = ((((size_t)(bh * 32 + sb)) * 2 + eta) * 4 + wv) * 512 + lane * 8;
      *(u16x8*)(Vf + off) = v;
    }
  }
}

// ---------------- K2: causal flash attention ----------------
// Block = q-tile pair (p, 63-p) run as 2 sequential phases -> UNIFORM block duration
// (~17 tile-units each). Per phase: 2 waves split kv, no barriers in loop, K and V
// prefetched IN PLACE right after their consumers issue (WAR handled by compiler).
// No-max exp2 softmax (C init -16), partials are pure sums.
__global__ __launch_bounds__(128, 2) void k_attn(
    const u16* __restrict__ Qf, const u16* __restrict__ Kf, const u16* __restrict__ Vf,
    u16* __restrict__ Co) {
  __shared__ float Xch[64][33];              // wave1 partials: o0[16], o1[16], ll
  __shared__ __align__(16) u16 Osw[32][64];  // wave0 epilogue transpose
  const int bid = blockIdx.x;
  const int xcd = bid & 7, idx = bid >> 3;   // idx 0..127; 4 bh per XCD (L2 locality)
  const int bh = (xcd << 2) | (idx & 3);
  const int pr = idx >> 2;                   // 0..31
  const int b = bh >> 4, h = bh & 15;
  const int w = threadIdx.x >> 6;
  const int l = threadIdx.x & 63;
  const int lq = l & 31, hi = l >> 5;
  const float NEG = -3.0e38f;

  const u16* Kbase = Kf + ((size_t)(bh * 64) * 4) * 512 + l * 8;
  const u16* Vbase = Vf + ((size_t)(bh * 32) * 8) * 512 + l * 8;

#pragma unroll 1
  for (int ph = 0; ph < 2; ++ph) {
    const int t = ph ? (63 - pr) : pr;
    const int qg = t * 32 + lq;
    const int n = (t >> 1) + 1;              // kv 64-tiles needed
    const int mid = n >> 1;
    const int jbeg = w ? mid : 0;
    const int jhot = w ? (n - 1) : mid;      // diag (j = n-1) peeled to wave1

    const u16* Qbase = Qf + (((size_t)(bh * 64 + t)) * 4) * 512 + l * 8;
    u16x8 qf[4];
#pragma unroll
    for (int ss = 0; ss < 4; ++ss) qf[ss] = *(const u16x8*)(Qbase + ss * 512);

    f32x16 o0, o1;
#pragma unroll
    for (int r = 0; r < 16; ++r) { o0[r] = 0.f; o1[r] = 0.f; }
    float ll = 0.f;

    u16x8 kl[4], kh[4], vl[4], vh[4];
    {
      const u16* pk = Kbase + (size_t)jbeg * 8 * 512;
      const u16* pv = Vbase + (size_t)jbeg * 8 * 512;
#pragma unroll
      for (int ss = 0; ss < 4; ++ss) {
        kl[ss] = *(const u16x8*)(pk + ss * 512);
        kh[ss] = *(const u16x8*)(pk + (4 + ss) * 512);
        vl[ss] = *(const u16x8*)(pv + ss * 512);
        vh[ss] = *(const u16x8*)(pv + (4 + ss) * 512);
      }
    }

    for (int j = jbeg; j < jhot; ++j) {
      f32x16 s0, s1;
#pragma unroll
      for (int r = 0; r < 16; ++r) { s0[r] = -16.f; s1[r] = -16.f; }
      __builtin_amdgcn_s_setprio(1);
      s0 = mfma32(kl[0], qf[0], s0);
      s0 = mfma32(kl[1], qf[1], s0);
      s0 = mfma32(kl[2], qf[2], s0);
      s0 = mfma32(kl[3], qf[3], s0);
      s1 = mfma32(kh[0], qf[0], s1);
      s1 = mfma32(kh[1], qf[1], s1);
      s1 = mfma32(kh[2], qf[2], s1);
      s1 = mfma32(kh[3], qf[3], s1);
      __builtin_amdgcn_s_setprio(0);
      {  // in-place K prefetch (j+1 <= n-1 always valid; last lands on diag tile)
        const u16* pk = Kbase + (size_t)(j + 1) * 8 * 512;
#pragma unroll
        for (int ss = 0; ss < 4; ++ss) {
          kl[ss] = *(const u16x8*)(pk + ss * 512);
          kh[ss] = *(const u16x8*)(pk + (4 + ss) * 512);
        }
      }
#pragma unroll
      for (int r = 0; r < 16; ++r) s0[r] = ex2(s0[r]);
#pragma unroll
      for (int r = 0; r < 16; ++r) s1[r] = ex2(s1[r]);
      u16x8 pf0, pf1, pf2, pf3;
      {
        unsigned w0, w1, w2, w3;
        pk_swap(s0[0], s0[1], s0[4], s0[5], w0, w2);
        pk_swap(s0[2], s0[3], s0[6], s0[7], w1, w3);
        pf0 = __builtin_bit_cast(u16x8, (u32x4){w0, w1, w2, w3});
        pk_swap(s0[8], s0[9], s0[12], s0[13], w0, w2);
        pk_swap(s0[10], s0[11], s0[14], s0[15], w1, w3);
        pf1 = __builtin_bit_cast(u16x8, (u32x4){w0, w1, w2, w3});
        pk_swap(s1[0], s1[1], s1[4], s1[5], w0, w2);
        pk_swap(s1[2], s1[3], s1[6], s1[7], w1, w3);
        pf2 = __builtin_bit_cast(u16x8, (u32x4){w0, w1, w2, w3});
        pk_swap(s1[8], s1[9], s1[12], s1[13], w0, w2);
        pk_swap(s1[10], s1[11], s1[14], s1[15], w1, w3);
        pf3 = __builtin_bit_cast(u16x8, (u32x4){w0, w1, w2, w3});
      }
      __builtin_amdgcn_s_setprio(1);
      o0 = mfma32(vl[0], pf0, o0);
      o1 = mfma32(vh[0], pf0, o1);
      o0 = mfma32(vl[1], pf1, o0);
      o1 = mfma32(vh[1], pf1, o1);
      o0 = mfma32(vl[2], pf2, o0);
      o1 = mfma32(vh[2], pf2, o1);
      o0 = mfma32(vl[3], pf3, o0);
      o1 = mfma32(vh[3], pf3, o1);
      __builtin_amdgcn_s_setprio(0);
      {  // in-place V prefetch
        const u16* pv = Vbase + (size_t)(j + 1) * 8 * 512;
#pragma unroll
        for (int ss = 0; ss < 4; ++ss) {
          vl[ss] = *(const u16x8*)(pv + ss * 512);
          vh[ss] = *(const u16x8*)(pv + (4 + ss) * 512);
        }
      }
      ll += tsum16(s0) + tsum16(s1);   // off the critical path (only needed at end)
    }

    if (w) {  // peeled diagonal tile j = n-1 (kl/kh/vl/vh already hold tile n-1)
      const int j = n - 1;
      f32x16 s0, s1;
#pragma unroll
      for (int r = 0; r < 16; ++r) { s0[r] = -16.f; s1[r] = -16.f; }
      s0 = mfma32(kl[0], qf[0], s0);
      s0 = mfma32(kl[1], qf[1], s0);
      s0 = mfma32(kl[2], qf[2], s0);
      s0 = mfma32(kl[3], qf[3], s0);
      if (t & 1) {
        s1 = mfma32(kh[0], qf[0], s1);
        s1 = mfma32(kh[1], qf[1], s1);
        s1 = mfma32(kh[2], qf[2], s1);
        s1 = mfma32(kh[3], qf[3], s1);
      }
      if (t & 1) {  // q in upper half: s0 unmasked, mask s1
#pragma unroll
        for (int r = 0; r < 16; ++r) {
          int kv = j * 64 + 32 + (r & 3) + 8 * (r >> 2) + 4 * hi;
          if (kv > qg) s1[r] = NEG;
        }
      } else {      // q in lower half: mask s0, skip s1
#pragma unroll
        for (int r = 0; r < 16; ++r) {
          int kv = j * 64 + (r & 3) + 8 * (r >> 2) + 4 * hi;
          if (kv > qg) s0[r] = NEG;
        }
      }
#pragma unroll
      for (int r = 0; r < 16; ++r) s0[r] = ex2(s0[r]);
      ll += tsum16(s0);
      if (t & 1) {
#pragma unroll
        for (int r = 0; r < 16; ++r) s1[r] = ex2(s1[r]);
        ll += tsum16(s1);
      }
      u16x8 pf0, pf1, pf2, pf3;
      {
        unsigned w0, w1, w2, w3;
        pk_swap(s0[0], s0[1], s0[4], s0[5], w0, w2);
        pk_swap(s0[2], s0[3], s0[6], s0[7], w1, w3);
        pf0 = __builtin_bit_cast(u16x8, (u32x4){w0, w1, w2, w3});
        pk_swap(s0[8], s0[9], s0[12], s0[13], w0, w2);
        pk_swap(s0[10], s0[11], s0[14], s0[15], w1, w3);
        pf1 = __builtin_bit_cast(u16x8, (u32x4){w0, w1, w2, w3});
        if (t & 1) {
          pk_swap(s1[0], s1[1], s1[4], s1[5], w0, w2);
          pk_swap(s1[2], s1[3], s1[6], s1[7], w1, w3);
          pf2 = __builtin_bit_cast(u16x8, (u32x4){w0, w1, w2, w3});
          pk_swap(s1[8], s1[9], s1[12], s1[13], w0, w2);
          pk_swap(s1[10], s1[11], s1[14], s1[15], w1, w3);
          pf3 = __builtin_bit_cast(u16x8, (u32x4){w0, w1, w2, w3});
        }
      }
      o0 = mfma32(vl[0], pf0, o0);
      o1 = mfma32(vh[0], pf0, o1);
      o0 = mfma32(vl[1], pf1, o0);
      o1 = mfma32(vh[1], pf1, o1);
      if (t & 1) {
        o0 = mfma32(vl[2], pf2, o0);
        o1 = mfma32(vh[2], pf2, o1);
        o0 = mfma32(vl[3], pf3, o0);
        o1 = mfma32(vh[3], pf3, o1);
      }
      // publish wave1 partials (pure sums)
#pragma unroll
      for (int r = 0; r < 16; ++r) { Xch[l][r] = o0[r]; Xch[l][16 + r] = o1[r]; }
      Xch[l][32] = ll;
    }
    __syncthreads();
    if (w == 0) {
#pragma unroll
      for (int r = 0; r < 16; ++r) { o0[r] += Xch[l][r]; o1[r] += Xch[l][16 + r]; }
      ll += Xch[l][32];
      ll += __shfl_xor(ll, 32);
      float inv = 1.0f / ll;
#pragma unroll
      for (int r = 0; r < 16; ++r) {
        int drow = (r & 3) + 8 * (r >> 2) + 4 * hi;
        *(u16*)swzb(Osw, lq, drow * 2) = f2bf(o0[r] * inv);
        *(u16*)swzb(Osw, lq, (32 + drow) * 2) = f2bf(o1[r] * inv);
      }
      u16* dst = Co + ((size_t)(b * S_ + qg)) * EMB_ + h * HS_ + hi * 32;
#pragma unroll
      for (int k = 0; k < 4; ++k) {
        u16x8 vv = *swzp(Osw, lq, (hi * 32 + k * 8) * 2);
        *(u16x8*)(dst + k * 8) = vv;
      }
    }
    __syncthreads();   // protect Xch before next phase's publish
  }
}

// ---------------- K3: out = concat @ Wo + bo (fp32 out), 64x128 tiles ----------------
__global__ __launch_bounds__(256) void k_outproj(
    const u16* __restrict__ Cc, const u16* __restrict__ Wot,
    const float* __restrict__ bo, float* __restrict__ out) {
  __shared__ __align__(16) u16 As[64][64];
  __shared__ __align__(16) u16 Bs[128][64];
  const int bid = blockIdx.x;
  const int xcd = bid & 7, sl = bid >> 3;
  const int mb = (xcd << 3) | (sl >> 3);
  const int nb = sl & 7;
  const int t = threadIdx.x;
  const int lane = t & 63, wv = t >> 6;
  const int lq = lane & 15, lg = lane >> 4;
  const int wr = wv >> 1, wc = wv & 1;
  const int srA = t >> 2, scA = (t & 3) << 4;
  const int srB = t >> 1, scB = (t & 1) << 5;
  f32x4 acc[2][4];
#pragma unroll
  for (int mi = 0; mi < 2; ++mi)
#pragma unroll
    for (int ni = 0; ni < 4; ++ni) { f32x4 z = {0.f, 0.f, 0.f, 0.f}; acc[mi][ni] = z; }
  const u16* abase = Cc + ((size_t)(mb * 64 + srA)) * EMB_ + scA;
  const u16* bbase = Wot + ((size_t)(nb * 128 + srB)) * EMB_ + scB;
  u16x8 ar[2], br[4];
#pragma unroll
  for (int q = 0; q < 2; ++q) ar[q] = *(const u16x8*)(abase + q * 8);
#pragma unroll
  for (int q = 0; q < 4; ++q) br[q] = *(const u16x8*)(bbase + q * 8);
  for (int kt = 0; kt < 16; ++kt) {
    __syncthreads();
#pragma unroll
    for (int q = 0; q < 2; ++q) *swzp(As, srA, (scA + q * 8) * 2) = ar[q];
#pragma unroll
    for (int q = 0; q < 4; ++q) *swzp(Bs, srB, (scB + q * 8) * 2) = br[q];
    __syncthreads();
    if (kt < 15) {
#pragma unroll
      for (int q = 0; q < 2; ++q) ar[q] = *(const u16x8*)(abase + (kt + 1) * 64 + q * 8);
#pragma unroll
      for (int q = 0; q < 4; ++q) br[q] = *(const u16x8*)(bbase + (kt + 1) * 64 + q * 8);
    }
#pragma unroll
    for (int kf = 0; kf < 2; ++kf) {
      u16x8 af[2], bf[4];
#pragma unroll
      for (int mi = 0; mi < 2; ++mi)
        af[mi] = *swzp(As, wr * 32 + mi * 16 + lq, kf * 64 + lg * 16);
#pragma unroll
      for (int ni = 0; ni < 4; ++ni)
        bf[ni] = *swzp(Bs, wc * 64 + ni * 16 + lq, kf * 64 + lg * 16);
#pragma unroll
      for (int mi = 0; mi < 2; ++mi)
#pragma unroll
        for (int ni = 0; ni < 4; ++ni)
          acc[mi][ni] = mfma16(af[mi], bf[ni], acc[mi][ni]);
    }
  }
#pragma unroll
  for (int mi = 0; mi < 2; ++mi) {
#pragma unroll
    for (int ni = 0; ni < 4; ++ni) {
      int col = nb * 128 + wc * 64 + ni * 16 + lq;
      float bv = bo[col];
#pragma unroll
      for (int rr = 0; rr < 4; ++rr) {
        int row = mb * 64 + wr * 32 + mi * 16 + lg * 4 + rr;
        out[(size_t)row * EMB_ + col] = acc[mi][ni][rr] + bv;
      }
    }
  }
}

extern "C" void kernel_launch(void* const* d_in, const int* in_sizes, int n_in,
                              void* d_out, int out_size, void* d_ws, size_t ws_size,
                              hipStream_t stream) {
  const float* xk = (const float*)d_in[0];
  const float* xv = (const float*)d_in[1];
  const float* xq = (const float*)d_in[2];
  const float* Wk = (const float*)d_in[3];
  const float* Wv = (const float*)d_in[4];
  const float* Wq = (const float*)d_in[5];
  const float* Wo = (const float*)d_in[6];
  const float* bo = (const float*)d_in[7];
  float* out = (float*)d_out;
  char* ws = (char*)d_ws;
  const size_t MB8 = (size_t)8 * 1024 * 1024;
  u16* Qfw = (u16*)(ws);             // fragment-major Q (pre-scaled, exp2 domain)
  u16* Kfw = (u16*)(ws + MB8);       // fragment-major K
  u16* Vfw = (u16*)(ws + 2 * MB8);   // fragment-major V^T
  u16* Cw  = (u16*)(ws + 3 * MB8);   // concat [2][2048][1024]
  u16* Wot = (u16*)(ws + 4 * MB8);   // [1024][1024]

  k_transpose_wo<<<dim3(16, 16), 256, 0, stream>>>(Wo, Wot);
  k_proj<<<dim3(32, 32, 3), 256, 0, stream>>>(xq, xk, xv, Wq, Wk, Wv, Qfw, Kfw, Vfw);
  k_attn<<<1024, 128, 0, stream>>>(Qfw, Kfw, Vfw, Cw);
  k_outproj<<<512, 256, 0, stream>>>(Cw, Wot, bo, out);
}